// Round 1
// baseline (932.608 us; speedup 1.0000x reference)
//
#include <hip/hip_runtime.h>

// Problem constants (from reference setup_inputs)
#define N_NODES 200000
#define N_EDGES 6400000
#define NGRAPH  128
#define H       32

// ---------------------------------------------------------------------------
// K0: h_global_graph = relu(x_global @ W_global + b_global)   [128, 32]
// ---------------------------------------------------------------------------
__global__ void k_global_enc(const float* __restrict__ xg,
                             const float* __restrict__ Wg,
                             const float* __restrict__ bg,
                             float* __restrict__ hg) {
    int tid = blockIdx.x * blockDim.x + threadIdx.x;
    if (tid >= NGRAPH * H) return;
    int b = tid >> 5, t = tid & 31;
    float acc = bg[t];
#pragma unroll
    for (int k = 0; k < 8; ++k)
        acc = fmaf(xg[b * 8 + k], Wg[k * H + t], acc);
    hg[tid] = fmaxf(acc, 0.f);
}

// ---------------------------------------------------------------------------
// K1: per-node encoder. 32 threads per node (8 nodes / 256-thread block).
// Produces m[n] = relu(h0 @ W_msg + b_msg)  (the per-source message, shared
// by ALL edges out of n, and also the self-loop contribution)
// and      s[n] = h0 @ W_self + b_self      (pre-relu self path).
// ---------------------------------------------------------------------------
__global__ void k_node_enc(const float* __restrict__ xl,
                           const int*   __restrict__ batch,
                           const float* __restrict__ hg,
                           const float* __restrict__ Wl,   const float* __restrict__ bl,
                           const float* __restrict__ Wmix, const float* __restrict__ bmix,
                           const float* __restrict__ Wmsg, const float* __restrict__ bmsg,
                           const float* __restrict__ Wself,const float* __restrict__ bself,
                           float* __restrict__ m, float* __restrict__ s) {
    __shared__ float hcat[8][96];   // per-node concat [h_local | h_global | h_int]
    __shared__ float h0s[8][32];

    int tid   = threadIdx.x;
    int local = tid >> 5;     // node within block
    int t     = tid & 31;     // feature
    int n     = blockIdx.x * 8 + local;   // 25000 blocks * 8 == 200000 exactly

    // h_local[t]
    float hl = bl[t];
#pragma unroll
    for (int k = 0; k < 16; ++k)
        hl = fmaf(xl[n * 16 + k], Wl[k * H + t], hl);
    hl = fmaxf(hl, 0.f);

    // h_global[t] via batch gather (hg already relu'd)
    float hgv = hg[batch[n] * H + t];

    hcat[local][t]      = hl;
    hcat[local][32 + t] = hgv;
    hcat[local][64 + t] = hl * hgv;
    __syncthreads();

    // h0[t] = relu(h_cat @ W_mix + b_mix)
    float h0 = bmix[t];
#pragma unroll
    for (int k = 0; k < 96; ++k)
        h0 = fmaf(hcat[local][k], Wmix[k * H + t], h0);
    h0 = fmaxf(h0, 0.f);
    h0s[local][t] = h0;
    __syncthreads();

    // m[t], s[t]
    float mv = bmsg[t], sv = bself[t];
#pragma unroll
    for (int k = 0; k < 32; ++k) {
        float hv = h0s[local][k];
        mv = fmaf(hv, Wmsg[k * H + t], mv);
        sv = fmaf(hv, Wself[k * H + t], sv);
    }
    m[n * H + t] = fmaxf(mv, 0.f);
    s[n * H + t] = sv;
}

// ---------------------------------------------------------------------------
// K2: edge scatter-add. One thread per (edge, feature).
// 32 consecutive lanes = one edge: coalesced 128B gather of m[src],
// 32 per-dword atomic adds into aggr[dst] (device-scope, L2-resident table).
// ---------------------------------------------------------------------------
__global__ void k_edge(const int* __restrict__ ei,
                       const float* __restrict__ m,
                       float* __restrict__ aggr) {
    int tid = blockIdx.x * blockDim.x + threadIdx.x;  // < E*32 = 204.8M < 2^31
    int e = tid >> 5;
    int t = tid & 31;
    if (e >= N_EDGES) return;
    int src = ei[e];             // row 0: src
    int dst = ei[N_EDGES + e];   // row 1: dst
    atomicAdd(&aggr[dst * H + t], m[src * H + t]);
}

// ---------------------------------------------------------------------------
// K3: h = relu(aggr + m + s)  (m = self-loop message), out = h @ W_out + b_out
// 32 threads per node; 2-class head via 32-lane shuffle reduction.
// ---------------------------------------------------------------------------
__global__ void k_final(const float* __restrict__ aggr,
                        const float* __restrict__ m,
                        const float* __restrict__ s,
                        const float* __restrict__ Wout,
                        const float* __restrict__ bout,
                        float* __restrict__ out) {
    int tid   = threadIdx.x;
    int local = tid >> 5;
    int t     = tid & 31;
    int n     = blockIdx.x * 8 + local;
    int i     = n * H + t;

    float h = fmaxf(aggr[i] + m[i] + s[i], 0.f);
    float p0 = h * Wout[t * 2 + 0];
    float p1 = h * Wout[t * 2 + 1];
#pragma unroll
    for (int off = 16; off >= 1; off >>= 1) {
        p0 += __shfl_down(p0, off, 32);
        p1 += __shfl_down(p1, off, 32);
    }
    if (t == 0) {
        out[n * 2 + 0] = p0 + bout[0];
        out[n * 2 + 1] = p1 + bout[1];
    }
}

// ---------------------------------------------------------------------------
extern "C" void kernel_launch(void* const* d_in, const int* in_sizes, int n_in,
                              void* d_out, int out_size, void* d_ws, size_t ws_size,
                              hipStream_t stream) {
    const float* xl    = (const float*)d_in[0];   // [N,16]
    const float* xg    = (const float*)d_in[1];   // [128,8]
    const int*   batch = (const int*)  d_in[2];   // [N]
    const int*   ei    = (const int*)  d_in[3];   // [2,E]
    const float* Wl    = (const float*)d_in[4];
    const float* bl    = (const float*)d_in[5];
    const float* Wg    = (const float*)d_in[6];
    const float* bg    = (const float*)d_in[7];
    const float* Wmix  = (const float*)d_in[8];
    const float* bmix  = (const float*)d_in[9];
    const float* Wmsg  = (const float*)d_in[10];
    const float* bmsg  = (const float*)d_in[11];
    const float* Wself = (const float*)d_in[12];
    const float* bself = (const float*)d_in[13];
    const float* Wout  = (const float*)d_in[14];
    const float* bout  = (const float*)d_in[15];
    float* out = (float*)d_out;

    // Workspace layout (floats): hg[128*32] | m[N*32] | s[N*32] | aggr[N*32]
    float* hg   = (float*)d_ws;
    float* m    = hg + NGRAPH * H;
    float* s    = m + (size_t)N_NODES * H;
    float* aggr = s + (size_t)N_NODES * H;

    // aggr must start at zero every call (ws is poisoned 0xAA by harness)
    hipMemsetAsync(aggr, 0, (size_t)N_NODES * H * sizeof(float), stream);

    k_global_enc<<<(NGRAPH * H + 255) / 256, 256, 0, stream>>>(xg, Wg, bg, hg);

    k_node_enc<<<N_NODES / 8, 256, 0, stream>>>(xl, batch, hg,
                                                Wl, bl, Wmix, bmix,
                                                Wmsg, bmsg, Wself, bself,
                                                m, s);

    // one thread per (edge, feature): E*32 threads
    long long edge_threads = (long long)N_EDGES * H;
    int edge_blocks = (int)((edge_threads + 255) / 256);
    k_edge<<<edge_blocks, 256, 0, stream>>>(ei, m, aggr);

    k_final<<<N_NODES / 8, 256, 0, stream>>>(aggr, m, s, Wout, bout, out);
}